// Round 7
// baseline (1490.539 us; speedup 1.0000x reference)
//
#include <hip/hip_runtime.h>
#include <hip/hip_bf16.h>

// Problem constants (from reference)
#define NPTS   160000    // B*P = 4*40000
#define DIM    128
#define HID    512
#define KK2    49        // 7x7
#define DEPTH  2

typedef __attribute__((ext_vector_type(8))) short bf16x8;
typedef __attribute__((ext_vector_type(4))) float f32x4;

static __device__ __forceinline__ ushort f2bf(float f) {
    unsigned u = __float_as_uint(f);
    return (ushort)((u + 0x7fffu + ((u >> 16) & 1u)) >> 16);
}
static __device__ __forceinline__ float bf2f(ushort h) {
    return __uint_as_float(((unsigned)h) << 16);
}
static __device__ __forceinline__ float lo16(unsigned u) { return __uint_as_float(u << 16); }
static __device__ __forceinline__ float hi16(unsigned u) { return __uint_as_float(u & 0xffff0000u); }

// async global->LDS copy, 16B per lane; LDS dest = wave-uniform base + lane*16
static __device__ __forceinline__ void cp16(const void* g, void* l) {
    __builtin_amdgcn_global_load_lds(
        (const __attribute__((address_space(1))) unsigned int*)g,
        (__attribute__((address_space(3))) unsigned int*)l,
        16, 0, 0);
}

// Fast GELU: exact form 0.5v(1+erf(v/sqrt2)) with A&S 7.1.26 erf
// (max |err| 1.5e-7 -- indistinguishable from libm erff at bf16 output).
static __device__ __forceinline__ float gelu_f(float v) {
    float x  = v * 0.70710678118654752f;
    float ax = fabsf(x);
    float t  = __builtin_amdgcn_rcpf(1.0f + 0.3275911f * ax);
    float p  = t * (0.254829592f + t * (-0.284496736f +
               t * (1.421413741f + t * (-1.453152027f + t * 1.061405429f))));
    float e  = __expf(-ax * ax);
    float er = copysignf(1.0f - p * e, x);
    return 0.5f * v * (1.0f + er);
}

// ---------------------------------------------------------------------------
// fp32 -> bf16 cast (4 elems/thread), exact-size grid
// ---------------------------------------------------------------------------
__global__ __launch_bounds__(256) void cast_bf16_kernel(
    const float* __restrict__ x, ushort* __restrict__ o)
{
    int i = blockIdx.x * 256 + threadIdx.x;
    float4 v = ((const float4*)x)[i];
    ushort4 r;
    r.x = f2bf(v.x); r.y = f2bf(v.y); r.z = f2bf(v.z); r.w = f2bf(v.w);
    ((ushort4*)o)[i] = r;
}

// ---------------------------------------------------------------------------
// w1 (128x512 fp32) -> w1sw: 512x128 bf16 n-major, PRE-SWIZZLED so that a
// linear global_load_lds copy reproduces the XOR-swizzled LDS image the GEMM
// read path expects.  Also zeros ssq.
// ---------------------------------------------------------------------------
__global__ void w1t_kernel(const float* __restrict__ w1, ushort* __restrict__ w1sw,
                           float* __restrict__ ssq) {
    int n = blockIdx.x;            // 0..511 (output col)
    int k = threadIdx.x;           // 0..127 (reduction dim)
    int c = k >> 3, jj = k & 7;
    int dst = ((n >> 7) << 14) + ((n & 127) << 7) + ((c ^ (n & 15)) << 3) + jj;
    w1sw[dst] = f2bf(w1[k * 512 + n]);
    if (n < 4) ssq[n * 128 + k] = 0.f;
}

// ---------------------------------------------------------------------------
// Compact valid neighbor taps:
//   entry = idx*256 + tap   (idx*256 = byte offset of X row; tap in low 8b)
// wl stride = 64 ints/token; row[lane] for lane >= cnt = 49 (idx 0, tap 49 =
// zero weight row -> unconditional gathers are safe).  cnts[n] = cnt.
// ---------------------------------------------------------------------------
__global__ __launch_bounds__(256) void compact2_kernel(
    const int* __restrict__ nbr, int* __restrict__ wl, int* __restrict__ cnts)
{
    const int tid = threadIdx.x, lane = tid & 63, wv = tid >> 6;
    const int n = blockIdx.x * 4 + wv;
    int idx = (lane < KK2) ? nbr[(size_t)n * KK2 + lane] : NPTS;
    bool valid = idx < NPTS;
    unsigned long long mask = __ballot(valid);
    int cnt = __popcll(mask);
    int pos = __popcll(mask & ((1ull << lane) - 1ull));
    int* row = wl + (size_t)n * 64;
    if (lane >= cnt) row[lane] = 49;              // disjoint from valid writes
    if (valid) row[pos] = (idx << 8) | lane;
    if (lane == 0) cnts[n] = cnt;
}

// ---------------------------------------------------------------------------
// Depthwise sparse conv + LayerNorm, v5 (unchanged): FOUR tokens per wave.
// ---------------------------------------------------------------------------
__global__ __launch_bounds__(1024, 8) void dwln5_kernel(
    const ushort* __restrict__ X,      // N x 128 bf16
    const int*    __restrict__ wl,     // N x 64 entries (padded with 49)
    const int*    __restrict__ cnts,   // N
    const float*  __restrict__ wdw,    // 49 x 128 fp32
    const float*  __restrict__ bdw,    // 128
    const float*  __restrict__ lng,    // 128
    const float*  __restrict__ lnb,    // 128
    ushort*       __restrict__ y1)     // N x 128 bf16
{
    __shared__ __align__(16) float wsm[16 * 404];   // [cg] stride 404, [tap][8]
    __shared__ int wle[64 * 68];                    // entry lists, stride 68
    const int tid = threadIdx.x;
    #pragma unroll
    for (int i0 = 0; i0 < 2048; i0 += 1024) {
        int i = i0 + tid;
        if (i < 1568) {
            int tap = i >> 5, rem = i & 31, cg = rem >> 1, q = rem & 1;
            ((float4*)wsm)[cg * 101 + tap * 2 + q] = ((const float4*)wdw)[i];
        }
    }
    if (tid < 32) {
        float4 z = {0.f, 0.f, 0.f, 0.f};
        int cg = tid >> 1, q = tid & 1;
        ((float4*)wsm)[cg * 101 + 98 + q] = z;     // tap 49 = zeros
    }
    {
        const int* src = wl + (size_t)blockIdx.x * 4096;
        #pragma unroll
        for (int m = 0; m < 4; ++m) {
            int idx = tid + (m << 10);
            wle[(idx >> 6) * 68 + (idx & 63)] = src[idx];
        }
    }
    __syncthreads();

    const int lane = tid & 63, wv = tid >> 6;
    const int g = lane >> 4, cg = lane & 15;
    const int li = (wv << 2) + g;                 // local token 0..63
    const int n = blockIdx.x * 64 + li;

    int myc = cnts[n];
    int rmax = max(myc, __shfl_xor(myc, 16));
    rmax = max(rmax, __shfl_xor(rmax, 32));

    const int* ep = wle + li * 68;
    const float* wcg = wsm + cg * 404;
    const char* Xb = (const char*)X + (cg << 4);

    float a[8] = {0.f, 0.f, 0.f, 0.f, 0.f, 0.f, 0.f, 0.f};

    int e0 = ep[0], e1 = ep[1], e2 = ep[2];
    uint4 x0 = *(const uint4*)(Xb + (e0 & ~255));
    uint4 x1 = *(const uint4*)(Xb + (e1 & ~255));
    uint4 x2 = *(const uint4*)(Xb + (e2 & ~255));

    for (int r = 0; r < rmax; ++r) {
        int e3 = ep[r + 3];                       // r+3 <= 51 < 64, broadcast
        uint4 x3 = *(const uint4*)(Xb + (e3 & ~255));
        const float* wp = wcg + (e0 & 255) * 8;
        float4 wa = *(const float4*)wp;
        float4 wb = *(const float4*)(wp + 4);
        a[0] += lo16(x0.x) * wa.x;  a[1] += hi16(x0.x) * wa.y;
        a[2] += lo16(x0.y) * wa.z;  a[3] += hi16(x0.y) * wa.w;
        a[4] += lo16(x0.z) * wb.x;  a[5] += hi16(x0.z) * wb.y;
        a[6] += lo16(x0.w) * wb.z;  a[7] += hi16(x0.w) * wb.w;
        e0 = e1; e1 = e2; e2 = e3;
        x0 = x1; x1 = x2; x2 = x3;
    }

    const float4 bda = ((const float4*)bdw)[cg * 2];
    const float4 bdb = ((const float4*)bdw)[cg * 2 + 1];
    a[0] += bda.x; a[1] += bda.y; a[2] += bda.z; a[3] += bda.w;
    a[4] += bdb.x; a[5] += bdb.y; a[6] += bdb.z; a[7] += bdb.w;

    float s1 = 0.f, s2 = 0.f;
    #pragma unroll
    for (int j = 0; j < 8; ++j) { s1 += a[j]; s2 += a[j] * a[j]; }
    #pragma unroll
    for (int m = 1; m < 16; m <<= 1) {
        s1 += __shfl_xor(s1, m);
        s2 += __shfl_xor(s2, m);
    }
    const float mu  = s1 * (1.f / 128.f);
    const float var = s2 * (1.f / 128.f) - mu * mu;
    const float rs  = rsqrtf(var + 1e-6f);

    const float4 ga = ((const float4*)lng)[cg * 2];
    const float4 gb = ((const float4*)lng)[cg * 2 + 1];
    const float4 ba = ((const float4*)lnb)[cg * 2];
    const float4 bb = ((const float4*)lnb)[cg * 2 + 1];
    uint4 r;
    r.x = (unsigned)f2bf((a[0] - mu) * rs * ga.x + ba.x)
        | ((unsigned)f2bf((a[1] - mu) * rs * ga.y + ba.y) << 16);
    r.y = (unsigned)f2bf((a[2] - mu) * rs * ga.z + ba.z)
        | ((unsigned)f2bf((a[3] - mu) * rs * ga.w + ba.w) << 16);
    r.z = (unsigned)f2bf((a[4] - mu) * rs * gb.x + bb.x)
        | ((unsigned)f2bf((a[5] - mu) * rs * gb.y + bb.y) << 16);
    r.w = (unsigned)f2bf((a[6] - mu) * rs * gb.z + bb.z)
        | ((unsigned)f2bf((a[7] - mu) * rs * gb.w + bb.w) << 16);
    ((uint4*)(y1 + (size_t)n * DIM))[cg] = r;      // all 64 lanes store
}

// ---------------------------------------------------------------------------
// GEMM1 v7: persistent-B, barrier-free.  Block = 1024 thr (16 waves), 1/CU.
// Entire pre-swizzled w1sw (128 KB) staged into LDS once via global_load_lds;
// after ONE barrier, each wave independently processes 16-row tiles
// (t = gw, gw+4096, ...): A frags -> per-ct {4 MFMA + GELU epilogue + ssq}.
// No barriers in the main loop: waves stream y1/y2 contiguously and the
// compiler can overlap next tile's A loads with the current epilogue.
// grid = 256.
// ---------------------------------------------------------------------------
__global__ __launch_bounds__(1024) void gemm1_kernel(
    const ushort* __restrict__ y1,    // N x 128 bf16
    const ushort* __restrict__ w1sw,  // 512 x 128 bf16 (n-major, pre-swizzled)
    const float*  __restrict__ b1,    // 512 fp32
    ushort*       __restrict__ y2,    // N x 512 bf16
    float*        __restrict__ ssq)   // 512 fp32
{
    __shared__ __align__(16) ushort sB[65536];   // 128 KB: 4 tiles of 128x128
    __shared__ float sred[HID];
    const int tid = threadIdx.x;
    const int lane = tid & 63, wv = tid >> 6;
    const int lr = lane & 15, q = lane >> 4;

    if (tid < HID) sred[tid] = 0.f;
    // stage all of B: wave wv covers LDS [wv*8KB, +8KB) in 8 x 1KB chunks
    {
        const char* g = (const char*)w1sw + (wv << 13) + (lane << 4);
        char* l = (char*)sB + (wv << 13);
        #pragma unroll
        for (int j = 0; j < 8; ++j)
            cp16(g + (j << 10), l + (j << 10));
    }
    __syncthreads();

    const int gw = blockIdx.x * 16 + wv;          // 0..4095
    for (int t = gw; t < NPTS / 16; t += 4096) {
        const int m0 = t << 4;
        // A fragments for 16 rows x K=128
        bf16x8 af[4];
        const ushort* a0 = y1 + (size_t)(m0 + lr) * DIM + (q << 3);
        #pragma unroll
        for (int ks = 0; ks < 4; ++ks)
            af[ks] = *(const bf16x8*)(a0 + ks * 32);

        #pragma unroll 1
        for (int ct = 0; ct < 32; ++ct) {
            const ushort* sb = sB + ((ct >> 3) << 14) + (((ct & 7) << 4) + lr) * 128;
            f32x4 acc = {0.f, 0.f, 0.f, 0.f};
            #pragma unroll
            for (int ks = 0; ks < 4; ++ks) {
                const int cidx = ((((ks << 2) + q) ^ lr) << 3);
                bf16x8 bfv = *(const bf16x8*)(sb + cidx);
                acc = __builtin_amdgcn_mfma_f32_16x16x32_bf16(af[ks], bfv, acc, 0, 0, 0);
            }
            const int col = (ct << 4) + lr;
            const float bv = b1[col];
            float ss = 0.f;
            #pragma unroll
            for (int r = 0; r < 4; ++r) {
                float g = gelu_f(acc[r] + bv);
                y2[(size_t)(m0 + (q << 2) + r) * HID + col] = f2bf(g);
                ss += g * g;
            }
            ss += __shfl_xor(ss, 16);
            ss += __shfl_xor(ss, 32);
            if (q == 0) atomicAdd(&sred[col], ss);
        }
    }

    __syncthreads();
    if (tid < HID) atomicAdd(&ssq[tid], sred[tid]);
}

// ---------------------------------------------------------------------------
// GRN scale: s[c] = grn_g[c] * nx[c] + 1
// ---------------------------------------------------------------------------
__global__ void grn_prep_kernel(const float* __restrict__ ssq,
                                const float* __restrict__ grn_g,
                                float* __restrict__ s)
{
    __shared__ float red[9];
    const int tid = threadIdx.x;
    const float gx = sqrtf(ssq[tid]);
    float v = gx;
    #pragma unroll
    for (int m = 1; m < 64; m <<= 1) v += __shfl_xor(v, m);
    if ((tid & 63) == 0) red[tid >> 6] = v;
    __syncthreads();
    if (tid == 0) {
        float t = 0.f;
        for (int i = 0; i < 8; ++i) t += red[i];
        red[8] = t;
    }
    __syncthreads();
    const float mean = red[8] * (1.f / 512.f);
    s[tid] = grn_g[tid] * (gx / (mean + 1e-6f)) + 1.0f;
}

// ---------------------------------------------------------------------------
// Fold GRN scale into w2 -> w2sw (n-major, bf16, PRE-SWIZZLED for linear
// global_load_lds staging) + constant bias vector.
// ---------------------------------------------------------------------------
__global__ __launch_bounds__(256) void prep_w2_kernel(
    const float* __restrict__ s,      // 512
    const float* __restrict__ w2,     // 512 x 128 fp32 (k-major)
    const float* __restrict__ grn_b,  // 512 fp32
    const float* __restrict__ b2,     // 128 fp32
    ushort*      __restrict__ w2sw,   // 128 x 512 bf16 (n-major, scaled, swz)
    float*       __restrict__ bvec)   // 128 fp32
{
    __shared__ float r4[4];
    const int j = blockIdx.x;
    const int tid = threadIdx.x;
    float part = 0.f;
    for (int k = tid; k < HID; k += 256) {
        float wv2 = w2[k * 128 + j];
        int kk = k >> 7, c = (k >> 3) & 15, jj = k & 7;
        w2sw[(kk << 14) + (j << 7) + ((c ^ (j & 15)) << 3) + jj] = f2bf(s[k] * wv2);
        part += grn_b[k] * wv2;
    }
    #pragma unroll
    for (int m = 1; m < 64; m <<= 1) part += __shfl_xor(part, m);
    if ((tid & 63) == 0) r4[tid >> 6] = part;
    __syncthreads();
    if (tid == 0)
        bvec[j] = r4[0] + r4[1] + r4[2] + r4[3] + b2[j];
}

// ---------------------------------------------------------------------------
// GEMM2 v7: persistent-B, barrier-free.  Block = 1024 thr (16 waves), 1/CU.
// Entire pre-swizzled w2sw (128 KB) staged once; each wave independently
// processes 16-row tiles: K=512 in 4 chunks (A frags reloaded per chunk,
// contiguous 16KB y2 stream per tile), acc[8] persists; epilogue adds
// bias + residual.  grid = 256.
// ---------------------------------------------------------------------------
__global__ __launch_bounds__(1024) void gemm2_kernel(
    const ushort* __restrict__ y2,      // N x 512 bf16
    const ushort* __restrict__ w2sw,    // 128 x 512 bf16 (n-major, swz)
    const float*  __restrict__ bvec,    // 128
    const ushort* __restrict__ resid,   // N x 128 bf16
    float*        __restrict__ outf,    // N x 128 fp32 (or null)
    ushort*       __restrict__ xbfout)  // N x 128 bf16 (or null)
{
    __shared__ __align__(16) ushort sB[65536];   // 128 KB: 4 k-chunks of 128x128
    const int tid = threadIdx.x;
    const int lane = tid & 63, wv = tid >> 6;
    const int lr = lane & 15, q = lane >> 4;

    {
        const char* g = (const char*)w2sw + (wv << 13) + (lane << 4);
        char* l = (char*)sB + (wv << 13);
        #pragma unroll
        for (int j = 0; j < 8; ++j)
            cp16(g + (j << 10), l + (j << 10));
    }
    __syncthreads();

    float bv[8];
    #pragma unroll
    for (int ct = 0; ct < 8; ++ct) bv[ct] = bvec[(ct << 4) + lr];

    const int gw = blockIdx.x * 16 + wv;          // 0..4095
    for (int t = gw; t < NPTS / 16; t += 4096) {
        const int m0 = t << 4;
        f32x4 acc[8];
        #pragma unroll
        for (int ct = 0; ct < 8; ++ct) { f32x4 z = {0.f,0.f,0.f,0.f}; acc[ct] = z; }

        const ushort* abase = y2 + (size_t)(m0 + lr) * HID + (q << 3);
        #pragma unroll
        for (int kc = 0; kc < 4; ++kc) {
            bf16x8 af[4];
            #pragma unroll
            for (int ks = 0; ks < 4; ++ks)
                af[ks] = *(const bf16x8*)(abase + (kc << 7) + ks * 32);
            #pragma unroll
            for (int ct = 0; ct < 8; ++ct) {
                const ushort* sb = sB + (kc << 14) + (((ct << 4) + lr) * 128);
                #pragma unroll
                for (int ks = 0; ks < 4; ++ks) {
                    const int cidx = ((((ks << 2) + q) ^ lr) << 3);
                    bf16x8 bfv = *(const bf16x8*)(sb + cidx);
                    acc[ct] = __builtin_amdgcn_mfma_f32_16x16x32_bf16(af[ks], bfv, acc[ct], 0, 0, 0);
                }
            }
        }

        #pragma unroll
        for (int r = 0; r < 4; ++r) {
            const int m = m0 + (q << 2) + r;
            const size_t base = (size_t)m * DIM;
            #pragma unroll
            for (int ct = 0; ct < 8; ++ct) {
                const int j = (ct << 4) + lr;
                float v = acc[ct][r] + bv[ct] + bf2f(resid[base + j]);
                if (outf)   outf[base + j] = v;
                if (xbfout) xbfout[base + j] = f2bf(v);
            }
        }
    }
}

// ---------------------------------------------------------------------------
extern "C" void kernel_launch(void* const* d_in, const int* in_sizes, int n_in,
                              void* d_out, int out_size, void* d_ws, size_t ws_size,
                              hipStream_t stream)
{
    const float* feats = (const float*)d_in[0];
    const float* w_dw  = (const float*)d_in[1];
    const float* b_dw  = (const float*)d_in[2];
    const float* ln_g  = (const float*)d_in[3];
    const float* ln_b  = (const float*)d_in[4];
    const float* w1    = (const float*)d_in[5];
    const float* b1    = (const float*)d_in[6];
    const float* grn_g = (const float*)d_in[7];
    const float* grn_b = (const float*)d_in[8];
    const float* w2    = (const float*)d_in[9];
    const float* b2    = (const float*)d_in[10];
    const int*   nbr   = (const int*)d_in[11];

    char* ws = (char*)d_ws;
    size_t o = 0;
    ushort* y2    = (ushort*)(ws + o); o += (size_t)NPTS * HID * 2;        // 160 MB
    ushort* y1    = (ushort*)(ws + o); o += (size_t)NPTS * DIM * 2;        //  40 MB
    ushort* xbf   = (ushort*)(ws + o); o += (size_t)NPTS * DIM * 2;        //  40 MB
    int*    wl    = (int*)   (ws + o); o += ((size_t)NPTS * 64 + 64) * 4;  //  41 MB
    int*    cnts  = (int*)   (ws + o); o += (size_t)NPTS * 4;
    ushort* w1sw  = (ushort*)(ws + o); o += (size_t)HID * DIM * 2;
    ushort* w2sw  = (ushort*)(ws + o); o += (size_t)HID * DIM * 2;
    float*  sbuf  = (float*) (ws + o); o += 2048;
    float*  ssq   = (float*) (ws + o); o += 2048;
    float*  bvec  = (float*) (ws + o); o += 512;

    cast_bf16_kernel<<<NPTS * DIM / 4 / 256, 256, 0, stream>>>(feats, xbf);
    compact2_kernel<<<NPTS / 4, 256, 0, stream>>>(nbr, wl, cnts);

    for (int l = 0; l < DEPTH; ++l) {
        const float* wdw_l = w_dw  + (size_t)l * KK2 * DIM;
        const float* bdw_l = b_dw  + (size_t)l * DIM;
        const float* lng_l = ln_g  + (size_t)l * DIM;
        const float* lnb_l = ln_b  + (size_t)l * DIM;
        const float* w1_l  = w1    + (size_t)l * DIM * HID;
        const float* b1_l  = b1    + (size_t)l * HID;
        const float* gg_l  = grn_g + (size_t)l * HID;
        const float* gb_l  = grn_b + (size_t)l * HID;
        const float* w2_l  = w2    + (size_t)l * HID * DIM;
        const float* b2_l  = b2    + (size_t)l * DIM;

        w1t_kernel<<<512, 128, 0, stream>>>(w1_l, w1sw, ssq);
        dwln5_kernel<<<NPTS / 64, 1024, 0, stream>>>(
            xbf, wl, cnts, wdw_l, bdw_l, lng_l, lnb_l, y1);
        gemm1_kernel<<<256, 1024, 0, stream>>>(y1, w1sw, b1_l, y2, ssq);
        grn_prep_kernel<<<1, 512, 0, stream>>>(ssq, gg_l, sbuf);
        prep_w2_kernel<<<128, 256, 0, stream>>>(sbuf, w2_l, gb_l, b2_l, w2sw, bvec);
        if (l == 0) {
            gemm2_kernel<<<256, 1024, 0, stream>>>(
                y2, w2sw, bvec, xbf, nullptr, xbf);
        } else {
            gemm2_kernel<<<256, 1024, 0, stream>>>(
                y2, w2sw, bvec, xbf, (float*)d_out, nullptr);
        }
    }
}

// Round 8
// 644.358 us; speedup vs baseline: 2.3132x; 2.3132x over previous
//
#include <hip/hip_runtime.h>
#include <hip/hip_bf16.h>

// Problem constants (from reference)
#define NPTS   160000    // B*P = 4*40000
#define DIM    128
#define HID    512
#define KK2    49        // 7x7
#define DEPTH  2

typedef __attribute__((ext_vector_type(8))) short bf16x8;
typedef __attribute__((ext_vector_type(4))) float f32x4;

static __device__ __forceinline__ ushort f2bf(float f) {
    unsigned u = __float_as_uint(f);
    return (ushort)((u + 0x7fffu + ((u >> 16) & 1u)) >> 16);
}
static __device__ __forceinline__ float bf2f(ushort h) {
    return __uint_as_float(((unsigned)h) << 16);
}
static __device__ __forceinline__ float lo16(unsigned u) { return __uint_as_float(u << 16); }
static __device__ __forceinline__ float hi16(unsigned u) { return __uint_as_float(u & 0xffff0000u); }

// async global->LDS copy, 16B per lane; LDS dest = wave-uniform base + lane*16
static __device__ __forceinline__ void cp16(const void* g, void* l) {
    __builtin_amdgcn_global_load_lds(
        (const __attribute__((address_space(1))) unsigned int*)g,
        (__attribute__((address_space(3))) unsigned int*)l,
        16, 0, 0);
}

// Fast GELU: exact form 0.5v(1+erf(v/sqrt2)) with A&S 7.1.26 erf
// (max |err| 1.5e-7 -- indistinguishable from libm erff at bf16 output).
static __device__ __forceinline__ float gelu_f(float v) {
    float x  = v * 0.70710678118654752f;
    float ax = fabsf(x);
    float t  = __builtin_amdgcn_rcpf(1.0f + 0.3275911f * ax);
    float p  = t * (0.254829592f + t * (-0.284496736f +
               t * (1.421413741f + t * (-1.453152027f + t * 1.061405429f))));
    float e  = __expf(-ax * ax);
    float er = copysignf(1.0f - p * e, x);
    return 0.5f * v * (1.0f + er);
}

// ---------------------------------------------------------------------------
// fp32 -> bf16 cast (4 elems/thread), exact-size grid
// ---------------------------------------------------------------------------
__global__ __launch_bounds__(256) void cast_bf16_kernel(
    const float* __restrict__ x, ushort* __restrict__ o)
{
    int i = blockIdx.x * 256 + threadIdx.x;
    float4 v = ((const float4*)x)[i];
    ushort4 r;
    r.x = f2bf(v.x); r.y = f2bf(v.y); r.z = f2bf(v.z); r.w = f2bf(v.w);
    ((ushort4*)o)[i] = r;
}

// ---------------------------------------------------------------------------
// w1 (128x512 fp32) -> w1sw: 512x128 bf16 n-major, PRE-SWIZZLED so that a
// linear global_load_lds copy reproduces the XOR-swizzled LDS image the GEMM
// read path expects.  Also zeros ssq.
// ---------------------------------------------------------------------------
__global__ void w1t_kernel(const float* __restrict__ w1, ushort* __restrict__ w1sw,
                           float* __restrict__ ssq) {
    int n = blockIdx.x;            // 0..511 (output col)
    int k = threadIdx.x;           // 0..127 (reduction dim)
    int c = k >> 3, jj = k & 7;
    int dst = ((n >> 7) << 14) + ((n & 127) << 7) + ((c ^ (n & 15)) << 3) + jj;
    w1sw[dst] = f2bf(w1[k * 512 + n]);
    if (n < 4) ssq[n * 128 + k] = 0.f;
}

// ---------------------------------------------------------------------------
// Compact valid neighbor taps:
//   entry = idx*256 + tap   (idx*256 = byte offset of X row; tap in low 8b)
// wl stride = 64 ints/token; row[lane] for lane >= cnt = 49 (idx 0, tap 49 =
// zero weight row -> unconditional gathers are safe).  cnts[n] = cnt.
// ---------------------------------------------------------------------------
__global__ __launch_bounds__(256) void compact2_kernel(
    const int* __restrict__ nbr, int* __restrict__ wl, int* __restrict__ cnts)
{
    const int tid = threadIdx.x, lane = tid & 63, wv = tid >> 6;
    const int n = blockIdx.x * 4 + wv;
    int idx = (lane < KK2) ? nbr[(size_t)n * KK2 + lane] : NPTS;
    bool valid = idx < NPTS;
    unsigned long long mask = __ballot(valid);
    int cnt = __popcll(mask);
    int pos = __popcll(mask & ((1ull << lane) - 1ull));
    int* row = wl + (size_t)n * 64;
    if (lane >= cnt) row[lane] = 49;              // disjoint from valid writes
    if (valid) row[pos] = (idx << 8) | lane;
    if (lane == 0) cnts[n] = cnt;
}

// ---------------------------------------------------------------------------
// Depthwise sparse conv + LayerNorm, v5 (unchanged): FOUR tokens per wave.
// ---------------------------------------------------------------------------
__global__ __launch_bounds__(1024, 8) void dwln5_kernel(
    const ushort* __restrict__ X,      // N x 128 bf16
    const int*    __restrict__ wl,     // N x 64 entries (padded with 49)
    const int*    __restrict__ cnts,   // N
    const float*  __restrict__ wdw,    // 49 x 128 fp32
    const float*  __restrict__ bdw,    // 128
    const float*  __restrict__ lng,    // 128
    const float*  __restrict__ lnb,    // 128
    ushort*       __restrict__ y1)     // N x 128 bf16
{
    __shared__ __align__(16) float wsm[16 * 404];   // [cg] stride 404, [tap][8]
    __shared__ int wle[64 * 68];                    // entry lists, stride 68
    const int tid = threadIdx.x;
    #pragma unroll
    for (int i0 = 0; i0 < 2048; i0 += 1024) {
        int i = i0 + tid;
        if (i < 1568) {
            int tap = i >> 5, rem = i & 31, cg = rem >> 1, q = rem & 1;
            ((float4*)wsm)[cg * 101 + tap * 2 + q] = ((const float4*)wdw)[i];
        }
    }
    if (tid < 32) {
        float4 z = {0.f, 0.f, 0.f, 0.f};
        int cg = tid >> 1, q = tid & 1;
        ((float4*)wsm)[cg * 101 + 98 + q] = z;     // tap 49 = zeros
    }
    {
        const int* src = wl + (size_t)blockIdx.x * 4096;
        #pragma unroll
        for (int m = 0; m < 4; ++m) {
            int idx = tid + (m << 10);
            wle[(idx >> 6) * 68 + (idx & 63)] = src[idx];
        }
    }
    __syncthreads();

    const int lane = tid & 63, wv = tid >> 6;
    const int g = lane >> 4, cg = lane & 15;
    const int li = (wv << 2) + g;                 // local token 0..63
    const int n = blockIdx.x * 64 + li;

    int myc = cnts[n];
    int rmax = max(myc, __shfl_xor(myc, 16));
    rmax = max(rmax, __shfl_xor(rmax, 32));

    const int* ep = wle + li * 68;
    const float* wcg = wsm + cg * 404;
    const char* Xb = (const char*)X + (cg << 4);

    float a[8] = {0.f, 0.f, 0.f, 0.f, 0.f, 0.f, 0.f, 0.f};

    int e0 = ep[0], e1 = ep[1], e2 = ep[2];
    uint4 x0 = *(const uint4*)(Xb + (e0 & ~255));
    uint4 x1 = *(const uint4*)(Xb + (e1 & ~255));
    uint4 x2 = *(const uint4*)(Xb + (e2 & ~255));

    for (int r = 0; r < rmax; ++r) {
        int e3 = ep[r + 3];                       // r+3 <= 51 < 64, broadcast
        uint4 x3 = *(const uint4*)(Xb + (e3 & ~255));
        const float* wp = wcg + (e0 & 255) * 8;
        float4 wa = *(const float4*)wp;
        float4 wb = *(const float4*)(wp + 4);
        a[0] += lo16(x0.x) * wa.x;  a[1] += hi16(x0.x) * wa.y;
        a[2] += lo16(x0.y) * wa.z;  a[3] += hi16(x0.y) * wa.w;
        a[4] += lo16(x0.z) * wb.x;  a[5] += hi16(x0.z) * wb.y;
        a[6] += lo16(x0.w) * wb.z;  a[7] += hi16(x0.w) * wb.w;
        e0 = e1; e1 = e2; e2 = e3;
        x0 = x1; x1 = x2; x2 = x3;
    }

    const float4 bda = ((const float4*)bdw)[cg * 2];
    const float4 bdb = ((const float4*)bdw)[cg * 2 + 1];
    a[0] += bda.x; a[1] += bda.y; a[2] += bda.z; a[3] += bda.w;
    a[4] += bdb.x; a[5] += bdb.y; a[6] += bdb.z; a[7] += bdb.w;

    float s1 = 0.f, s2 = 0.f;
    #pragma unroll
    for (int j = 0; j < 8; ++j) { s1 += a[j]; s2 += a[j] * a[j]; }
    #pragma unroll
    for (int m = 1; m < 16; m <<= 1) {
        s1 += __shfl_xor(s1, m);
        s2 += __shfl_xor(s2, m);
    }
    const float mu  = s1 * (1.f / 128.f);
    const float var = s2 * (1.f / 128.f) - mu * mu;
    const float rs  = rsqrtf(var + 1e-6f);

    const float4 ga = ((const float4*)lng)[cg * 2];
    const float4 gb = ((const float4*)lng)[cg * 2 + 1];
    const float4 ba = ((const float4*)lnb)[cg * 2];
    const float4 bb = ((const float4*)lnb)[cg * 2 + 1];
    uint4 r;
    r.x = (unsigned)f2bf((a[0] - mu) * rs * ga.x + ba.x)
        | ((unsigned)f2bf((a[1] - mu) * rs * ga.y + ba.y) << 16);
    r.y = (unsigned)f2bf((a[2] - mu) * rs * ga.z + ba.z)
        | ((unsigned)f2bf((a[3] - mu) * rs * ga.w + ba.w) << 16);
    r.z = (unsigned)f2bf((a[4] - mu) * rs * gb.x + bb.x)
        | ((unsigned)f2bf((a[5] - mu) * rs * gb.y + bb.y) << 16);
    r.w = (unsigned)f2bf((a[6] - mu) * rs * gb.z + bb.z)
        | ((unsigned)f2bf((a[7] - mu) * rs * gb.w + bb.w) << 16);
    ((uint4*)(y1 + (size_t)n * DIM))[cg] = r;      // all 64 lanes store
}

// ---------------------------------------------------------------------------
// GEMM1 v8 = v6 structure with 8-wave blocks (512 thr, 16 rows/wave).
// Same 128-row block tile, same single 32KB XOR-swizzled sB staged via
// global_load_lds, same contiguous L3-friendly access order (v7's machine-
// wide scatter caused 4-6x HBM amplification -- reverted).  Halved per-wave
// register state (VGPR ~104 -> ~80) raises waves/CU ~16 -> ~24 to hide the
// A-load + stage latency.  grid = NPTS/128.
// ---------------------------------------------------------------------------
__global__ __launch_bounds__(512) void gemm1_kernel(
    const ushort* __restrict__ y1,    // N x 128 bf16
    const ushort* __restrict__ w1sw,  // 512 x 128 bf16 (n-major, pre-swizzled)
    const float*  __restrict__ b1,    // 512 fp32
    ushort*       __restrict__ y2,    // N x 512 bf16
    float*        __restrict__ ssq)   // 512 fp32
{
    __shared__ __align__(16) ushort sB[128 * 128];   // 32 KB
    __shared__ float sred[HID];
    const int tid = threadIdx.x;
    const int lane = tid & 63, wv = tid >> 6;        // wv 0..7
    const int lr = lane & 15, q = lane >> 4;
    const int m0 = blockIdx.x << 7;
    const int mw = m0 + (wv << 4);                   // 16 rows per wave

    if (tid < HID) sred[tid] = 0.f;

    // A fragments: lane holds row (mw + lr), k = ks*32 + q*8 .. +8
    bf16x8 af[4];
    {
        const ushort* a0 = y1 + (size_t)(mw + lr) * DIM + (q << 3);
        #pragma unroll
        for (int ks = 0; ks < 4; ++ks)
            af[ks] = *(const bf16x8*)(a0 + ks * 32);
    }

    #pragma unroll 1
    for (int nt = 0; nt < 4; ++nt) {
        // async stage B n-tile: wave wv covers LDS [wv*4KB, +4KB) in 4x1KB
        {
            const char* gsrc = (const char*)w1sw + (nt << 15) + (wv << 12) + (lane << 4);
            char* lb = (char*)sB + (wv << 12);
            #pragma unroll
            for (int j = 0; j < 4; ++j)
                cp16(gsrc + (j << 10), lb + (j << 10));
        }
        float b1v[8];
        #pragma unroll
        for (int ct = 0; ct < 8; ++ct) b1v[ct] = b1[(nt << 7) + (ct << 4) + lr];
        __syncthreads();

        f32x4 acc[8];
        #pragma unroll
        for (int ct = 0; ct < 8; ++ct) { f32x4 z = {0.f,0.f,0.f,0.f}; acc[ct] = z; }

        #pragma unroll
        for (int ct = 0; ct < 8; ++ct)
            #pragma unroll
            for (int ks = 0; ks < 4; ++ks) {
                const int cidx = ((((ks << 2) + q) ^ lr) << 3);
                bf16x8 bfv = *(const bf16x8*)(sB + ((ct << 4) + lr) * 128 + cidx);
                acc[ct] = __builtin_amdgcn_mfma_f32_16x16x32_bf16(af[ks], bfv, acc[ct], 0, 0, 0);
            }

        // epilogue for this n-tile: bias + fast GELU + store + ssq partials
        #pragma unroll
        for (int ct = 0; ct < 8; ++ct) {
            const int col = (nt << 7) + (ct << 4) + lr;
            float ss = 0.f;
            #pragma unroll
            for (int r = 0; r < 4; ++r) {
                float g = gelu_f(acc[ct][r] + b1v[ct]);
                y2[(size_t)(mw + (q << 2) + r) * HID + col] = f2bf(g);
                ss += g * g;
            }
            ss += __shfl_xor(ss, 16);
            ss += __shfl_xor(ss, 32);
            if (q == 0) atomicAdd(&sred[col], ss);
        }
        __syncthreads();
    }

    if (tid < HID) atomicAdd(&ssq[tid], sred[tid]);
}

// ---------------------------------------------------------------------------
// GRN scale: s[c] = grn_g[c] * nx[c] + 1
// ---------------------------------------------------------------------------
__global__ void grn_prep_kernel(const float* __restrict__ ssq,
                                const float* __restrict__ grn_g,
                                float* __restrict__ s)
{
    __shared__ float red[9];
    const int tid = threadIdx.x;
    const float gx = sqrtf(ssq[tid]);
    float v = gx;
    #pragma unroll
    for (int m = 1; m < 64; m <<= 1) v += __shfl_xor(v, m);
    if ((tid & 63) == 0) red[tid >> 6] = v;
    __syncthreads();
    if (tid == 0) {
        float t = 0.f;
        for (int i = 0; i < 8; ++i) t += red[i];
        red[8] = t;
    }
    __syncthreads();
    const float mean = red[8] * (1.f / 512.f);
    s[tid] = grn_g[tid] * (gx / (mean + 1e-6f)) + 1.0f;
}

// ---------------------------------------------------------------------------
// Fold GRN scale into w2 -> w2sw (n-major, bf16, PRE-SWIZZLED for linear
// global_load_lds staging) + constant bias vector.
// ---------------------------------------------------------------------------
__global__ __launch_bounds__(256) void prep_w2_kernel(
    const float* __restrict__ s,      // 512
    const float* __restrict__ w2,     // 512 x 128 fp32 (k-major)
    const float* __restrict__ grn_b,  // 512 fp32
    const float* __restrict__ b2,     // 128 fp32
    ushort*      __restrict__ w2sw,   // 128 x 512 bf16 (n-major, scaled, swz)
    float*       __restrict__ bvec)   // 128 fp32
{
    __shared__ float r4[4];
    const int j = blockIdx.x;
    const int tid = threadIdx.x;
    float part = 0.f;
    for (int k = tid; k < HID; k += 256) {
        float wv2 = w2[k * 128 + j];
        int kk = k >> 7, c = (k >> 3) & 15, jj = k & 7;
        w2sw[(kk << 14) + (j << 7) + ((c ^ (j & 15)) << 3) + jj] = f2bf(s[k] * wv2);
        part += grn_b[k] * wv2;
    }
    #pragma unroll
    for (int m = 1; m < 64; m <<= 1) part += __shfl_xor(part, m);
    if ((tid & 63) == 0) r4[tid >> 6] = part;
    __syncthreads();
    if (tid == 0)
        bvec[j] = r4[0] + r4[1] + r4[2] + r4[3] + b2[j];
}

// ---------------------------------------------------------------------------
// GEMM2 v8 = v6 structure with 8-wave blocks (512 thr, 16 rows/wave).
// Single 32KB sB restaged per K-chunk via global_load_lds; A direct
// global->reg issued before the stage.  Halved per-wave state (acc[8] = 32
// VGPR) raises occupancy to hide the A-chunk load latency.  grid = NPTS/128.
// ---------------------------------------------------------------------------
__global__ __launch_bounds__(512) void gemm2_kernel(
    const ushort* __restrict__ y2,      // N x 512 bf16
    const ushort* __restrict__ w2sw,    // 128 x 512 bf16 (n-major, swz)
    const float*  __restrict__ bvec,    // 128
    const ushort* __restrict__ resid,   // N x 128 bf16
    float*        __restrict__ outf,    // N x 128 fp32 (or null)
    ushort*       __restrict__ xbfout)  // N x 128 bf16 (or null)
{
    __shared__ __align__(16) ushort sB[128 * 128];   // 32 KB: 128 n x 128 k chunk
    const int tid = threadIdx.x;
    const int lane = tid & 63, wv = tid >> 6;        // wv 0..7
    const int lr = lane & 15, q = lane >> 4;
    const int m0 = blockIdx.x << 7;
    const int mw = m0 + (wv << 4);                   // 16 rows per wave

    f32x4 acc[8];
    #pragma unroll
    for (int ct = 0; ct < 8; ++ct) { f32x4 z = {0.f,0.f,0.f,0.f}; acc[ct] = z; }

    const ushort* abase = y2 + (size_t)(mw + lr) * HID + (q << 3);

    #pragma unroll 1
    for (int kk = 0; kk < 4; ++kk) {
        // A frags for this K-chunk: issue first so HBM latency overlaps staging
        bf16x8 af[4];
        #pragma unroll
        for (int ks = 0; ks < 4; ++ks)
            af[ks] = *(const bf16x8*)(abase + (kk << 7) + ks * 32);

        // async stage B chunk: wave wv covers LDS [wv*4KB, +4KB) in 4x1KB
        {
            const char* gsrc = (const char*)w2sw + (kk << 15) + (wv << 12) + (lane << 4);
            char* lb = (char*)sB + (wv << 12);
            #pragma unroll
            for (int j = 0; j < 4; ++j)
                cp16(gsrc + (j << 10), lb + (j << 10));
        }
        __syncthreads();

        #pragma unroll
        for (int ct = 0; ct < 8; ++ct)
            #pragma unroll
            for (int ks = 0; ks < 4; ++ks) {
                const int cidx = ((((ks << 2) + q) ^ lr) << 3);
                bf16x8 bfv = *(const bf16x8*)(sB + ((ct << 4) + lr) * 128 + cidx);
                acc[ct] = __builtin_amdgcn_mfma_f32_16x16x32_bf16(af[ks], bfv, acc[ct], 0, 0, 0);
            }
        __syncthreads();
    }

    float bv[8];
    #pragma unroll
    for (int ct = 0; ct < 8; ++ct) bv[ct] = bvec[(ct << 4) + lr];

    #pragma unroll
    for (int r = 0; r < 4; ++r) {
        const int m = mw + (q << 2) + r;
        const size_t base = (size_t)m * DIM;
        #pragma unroll
        for (int ct = 0; ct < 8; ++ct) {
            const int j = (ct << 4) + lr;
            float v = acc[ct][r] + bv[ct] + bf2f(resid[base + j]);
            if (outf)   outf[base + j] = v;
            if (xbfout) xbfout[base + j] = f2bf(v);
        }
    }
}

// ---------------------------------------------------------------------------
extern "C" void kernel_launch(void* const* d_in, const int* in_sizes, int n_in,
                              void* d_out, int out_size, void* d_ws, size_t ws_size,
                              hipStream_t stream)
{
    const float* feats = (const float*)d_in[0];
    const float* w_dw  = (const float*)d_in[1];
    const float* b_dw  = (const float*)d_in[2];
    const float* ln_g  = (const float*)d_in[3];
    const float* ln_b  = (const float*)d_in[4];
    const float* w1    = (const float*)d_in[5];
    const float* b1    = (const float*)d_in[6];
    const float* grn_g = (const float*)d_in[7];
    const float* grn_b = (const float*)d_in[8];
    const float* w2    = (const float*)d_in[9];
    const float* b2    = (const float*)d_in[10];
    const int*   nbr   = (const int*)d_in[11];

    char* ws = (char*)d_ws;
    size_t o = 0;
    ushort* y2    = (ushort*)(ws + o); o += (size_t)NPTS * HID * 2;        // 160 MB
    ushort* y1    = (ushort*)(ws + o); o += (size_t)NPTS * DIM * 2;        //  40 MB
    ushort* xbf   = (ushort*)(ws + o); o += (size_t)NPTS * DIM * 2;        //  40 MB
    int*    wl    = (int*)   (ws + o); o += ((size_t)NPTS * 64 + 64) * 4;  //  41 MB
    int*    cnts  = (int*)   (ws + o); o += (size_t)NPTS * 4;
    ushort* w1sw  = (ushort*)(ws + o); o += (size_t)HID * DIM * 2;
    ushort* w2sw  = (ushort*)(ws + o); o += (size_t)HID * DIM * 2;
    float*  sbuf  = (float*) (ws + o); o += 2048;
    float*  ssq   = (float*) (ws + o); o += 2048;
    float*  bvec  = (float*) (ws + o); o += 512;

    cast_bf16_kernel<<<NPTS * DIM / 4 / 256, 256, 0, stream>>>(feats, xbf);
    compact2_kernel<<<NPTS / 4, 256, 0, stream>>>(nbr, wl, cnts);

    for (int l = 0; l < DEPTH; ++l) {
        const float* wdw_l = w_dw  + (size_t)l * KK2 * DIM;
        const float* bdw_l = b_dw  + (size_t)l * DIM;
        const float* lng_l = ln_g  + (size_t)l * DIM;
        const float* lnb_l = ln_b  + (size_t)l * DIM;
        const float* w1_l  = w1    + (size_t)l * DIM * HID;
        const float* b1_l  = b1    + (size_t)l * HID;
        const float* gg_l  = grn_g + (size_t)l * HID;
        const float* gb_l  = grn_b + (size_t)l * HID;
        const float* w2_l  = w2    + (size_t)l * HID * DIM;
        const float* b2_l  = b2    + (size_t)l * DIM;

        w1t_kernel<<<512, 128, 0, stream>>>(w1_l, w1sw, ssq);
        dwln5_kernel<<<NPTS / 64, 1024, 0, stream>>>(
            xbf, wl, cnts, wdw_l, bdw_l, lng_l, lnb_l, y1);
        gemm1_kernel<<<NPTS / 128, 512, 0, stream>>>(y1, w1sw, b1_l, y2, ssq);
        grn_prep_kernel<<<1, 512, 0, stream>>>(ssq, gg_l, sbuf);
        prep_w2_kernel<<<128, 256, 0, stream>>>(sbuf, w2_l, gb_l, b2_l, w2sw, bvec);
        if (l == 0) {
            gemm2_kernel<<<NPTS / 128, 512, 0, stream>>>(
                y2, w2sw, bvec, xbf, nullptr, xbf);
        } else {
            gemm2_kernel<<<NPTS / 128, 512, 0, stream>>>(
                y2, w2sw, bvec, xbf, (float*)d_out, nullptr);
        }
    }
}

// Round 9
// 613.950 us; speedup vs baseline: 2.4278x; 1.0495x over previous
//
#include <hip/hip_runtime.h>
#include <hip/hip_bf16.h>

// Problem constants (from reference)
#define NPTS   160000    // B*P = 4*40000
#define DIM    128
#define HID    512
#define KK2    49        // 7x7
#define DEPTH  2

typedef __attribute__((ext_vector_type(8))) short bf16x8;
typedef __attribute__((ext_vector_type(4))) float f32x4;

static __device__ __forceinline__ ushort f2bf(float f) {
    unsigned u = __float_as_uint(f);
    return (ushort)((u + 0x7fffu + ((u >> 16) & 1u)) >> 16);
}
static __device__ __forceinline__ float bf2f(ushort h) {
    return __uint_as_float(((unsigned)h) << 16);
}
static __device__ __forceinline__ float lo16(unsigned u) { return __uint_as_float(u << 16); }
static __device__ __forceinline__ float hi16(unsigned u) { return __uint_as_float(u & 0xffff0000u); }

// HW packed f32->bf16 convert (RTNE, same rounding as f2bf): 1 VALU op
// replaces the 5-op manual rounding (and ~10-op pair packs).
static __device__ __forceinline__ unsigned cvt_pk_bf16(float lo, float hi) {
    unsigned r;
    asm("v_cvt_pk_bf16_f32 %0, %1, %2" : "=v"(r) : "v"(lo), "v"(hi));
    return r;
}

// async global->LDS copy, 16B per lane; LDS dest = wave-uniform base + lane*16
static __device__ __forceinline__ void cp16(const void* g, void* l) {
    __builtin_amdgcn_global_load_lds(
        (const __attribute__((address_space(1))) unsigned int*)g,
        (__attribute__((address_space(3))) unsigned int*)l,
        16, 0, 0);
}

// GELU, tanh form folded to 7 VALU ops (one v_exp, no fabs/copysign):
//   gelu(v) = v - v / (exp2(v*(a + b v^2)) + 1),  a=2*log2e*0.79788456,
//   b = a*0.044715.  Max |diff| vs exact-erf GELU ~3e-4 -- an order below
//   bf16 ulp at the magnitudes involved.  Branch-free, saturates correctly.
static __device__ __forceinline__ float gelu_f(float v) {
    float x2 = v * v;
    float u  = v * fmaf(x2, 0.1029435f, 2.3022082f);
    float t  = __builtin_amdgcn_exp2f(u);
    float r  = __builtin_amdgcn_rcpf(t + 1.0f);
    return fmaf(-v, r, v);
}

// ---------------------------------------------------------------------------
// fp32 -> bf16 cast (4 elems/thread), exact-size grid
// ---------------------------------------------------------------------------
__global__ __launch_bounds__(256) void cast_bf16_kernel(
    const float* __restrict__ x, ushort* __restrict__ o)
{
    int i = blockIdx.x * 256 + threadIdx.x;
    float4 v = ((const float4*)x)[i];
    uint2 r;
    r.x = cvt_pk_bf16(v.x, v.y);
    r.y = cvt_pk_bf16(v.z, v.w);
    ((uint2*)o)[i] = r;
}

// ---------------------------------------------------------------------------
// w1 (128x512 fp32) -> w1sw: 512x128 bf16 n-major, PRE-SWIZZLED so that a
// linear global_load_lds copy reproduces the XOR-swizzled LDS image the GEMM
// read path expects.  Also zeros ssq.
// ---------------------------------------------------------------------------
__global__ void w1t_kernel(const float* __restrict__ w1, ushort* __restrict__ w1sw,
                           float* __restrict__ ssq) {
    int n = blockIdx.x;            // 0..511 (output col)
    int k = threadIdx.x;           // 0..127 (reduction dim)
    int c = k >> 3, jj = k & 7;
    int dst = ((n >> 7) << 14) + ((n & 127) << 7) + ((c ^ (n & 15)) << 3) + jj;
    w1sw[dst] = f2bf(w1[k * 512 + n]);
    if (n < 4) ssq[n * 128 + k] = 0.f;
}

// ---------------------------------------------------------------------------
// Compact valid neighbor taps:
//   entry = idx*256 + tap   (idx*256 = byte offset of X row; tap in low 8b)
// wl stride = 64 ints/token; row[lane] for lane >= cnt = 49 (idx 0, tap 49 =
// zero weight row -> unconditional gathers are safe).  cnts[n] = cnt.
// ---------------------------------------------------------------------------
__global__ __launch_bounds__(256) void compact2_kernel(
    const int* __restrict__ nbr, int* __restrict__ wl, int* __restrict__ cnts)
{
    const int tid = threadIdx.x, lane = tid & 63, wv = tid >> 6;
    const int n = blockIdx.x * 4 + wv;
    int idx = (lane < KK2) ? nbr[(size_t)n * KK2 + lane] : NPTS;
    bool valid = idx < NPTS;
    unsigned long long mask = __ballot(valid);
    int cnt = __popcll(mask);
    int pos = __popcll(mask & ((1ull << lane) - 1ull));
    int* row = wl + (size_t)n * 64;
    if (lane >= cnt) row[lane] = 49;              // disjoint from valid writes
    if (valid) row[pos] = (idx << 8) | lane;
    if (lane == 0) cnts[n] = cnt;
}

// ---------------------------------------------------------------------------
// Depthwise sparse conv + LayerNorm, v5 + cvt_pk pack epilogue.
// ---------------------------------------------------------------------------
__global__ __launch_bounds__(1024, 8) void dwln5_kernel(
    const ushort* __restrict__ X,      // N x 128 bf16
    const int*    __restrict__ wl,     // N x 64 entries (padded with 49)
    const int*    __restrict__ cnts,   // N
    const float*  __restrict__ wdw,    // 49 x 128 fp32
    const float*  __restrict__ bdw,    // 128
    const float*  __restrict__ lng,    // 128
    const float*  __restrict__ lnb,    // 128
    ushort*       __restrict__ y1)     // N x 128 bf16
{
    __shared__ __align__(16) float wsm[16 * 404];   // [cg] stride 404, [tap][8]
    __shared__ int wle[64 * 68];                    // entry lists, stride 68
    const int tid = threadIdx.x;
    #pragma unroll
    for (int i0 = 0; i0 < 2048; i0 += 1024) {
        int i = i0 + tid;
        if (i < 1568) {
            int tap = i >> 5, rem = i & 31, cg = rem >> 1, q = rem & 1;
            ((float4*)wsm)[cg * 101 + tap * 2 + q] = ((const float4*)wdw)[i];
        }
    }
    if (tid < 32) {
        float4 z = {0.f, 0.f, 0.f, 0.f};
        int cg = tid >> 1, q = tid & 1;
        ((float4*)wsm)[cg * 101 + 98 + q] = z;     // tap 49 = zeros
    }
    {
        const int* src = wl + (size_t)blockIdx.x * 4096;
        #pragma unroll
        for (int m = 0; m < 4; ++m) {
            int idx = tid + (m << 10);
            wle[(idx >> 6) * 68 + (idx & 63)] = src[idx];
        }
    }
    __syncthreads();

    const int lane = tid & 63, wv = tid >> 6;
    const int g = lane >> 4, cg = lane & 15;
    const int li = (wv << 2) + g;                 // local token 0..63
    const int n = blockIdx.x * 64 + li;

    int myc = cnts[n];
    int rmax = max(myc, __shfl_xor(myc, 16));
    rmax = max(rmax, __shfl_xor(rmax, 32));

    const int* ep = wle + li * 68;
    const float* wcg = wsm + cg * 404;
    const char* Xb = (const char*)X + (cg << 4);

    float a[8] = {0.f, 0.f, 0.f, 0.f, 0.f, 0.f, 0.f, 0.f};

    int e0 = ep[0], e1 = ep[1], e2 = ep[2];
    uint4 x0 = *(const uint4*)(Xb + (e0 & ~255));
    uint4 x1 = *(const uint4*)(Xb + (e1 & ~255));
    uint4 x2 = *(const uint4*)(Xb + (e2 & ~255));

    for (int r = 0; r < rmax; ++r) {
        int e3 = ep[r + 3];                       // r+3 <= 51 < 64, broadcast
        uint4 x3 = *(const uint4*)(Xb + (e3 & ~255));
        const float* wp = wcg + (e0 & 255) * 8;
        float4 wa = *(const float4*)wp;
        float4 wb = *(const float4*)(wp + 4);
        a[0] += lo16(x0.x) * wa.x;  a[1] += hi16(x0.x) * wa.y;
        a[2] += lo16(x0.y) * wa.z;  a[3] += hi16(x0.y) * wa.w;
        a[4] += lo16(x0.z) * wb.x;  a[5] += hi16(x0.z) * wb.y;
        a[6] += lo16(x0.w) * wb.z;  a[7] += hi16(x0.w) * wb.w;
        e0 = e1; e1 = e2; e2 = e3;
        x0 = x1; x1 = x2; x2 = x3;
    }

    const float4 bda = ((const float4*)bdw)[cg * 2];
    const float4 bdb = ((const float4*)bdw)[cg * 2 + 1];
    a[0] += bda.x; a[1] += bda.y; a[2] += bda.z; a[3] += bda.w;
    a[4] += bdb.x; a[5] += bdb.y; a[6] += bdb.z; a[7] += bdb.w;

    float s1 = 0.f, s2 = 0.f;
    #pragma unroll
    for (int j = 0; j < 8; ++j) { s1 += a[j]; s2 += a[j] * a[j]; }
    #pragma unroll
    for (int m = 1; m < 16; m <<= 1) {
        s1 += __shfl_xor(s1, m);
        s2 += __shfl_xor(s2, m);
    }
    const float mu  = s1 * (1.f / 128.f);
    const float var = s2 * (1.f / 128.f) - mu * mu;
    const float rs  = rsqrtf(var + 1e-6f);

    const float4 ga = ((const float4*)lng)[cg * 2];
    const float4 gb = ((const float4*)lng)[cg * 2 + 1];
    const float4 ba = ((const float4*)lnb)[cg * 2];
    const float4 bb = ((const float4*)lnb)[cg * 2 + 1];
    uint4 r;
    r.x = cvt_pk_bf16((a[0] - mu) * rs * ga.x + ba.x,
                      (a[1] - mu) * rs * ga.y + ba.y);
    r.y = cvt_pk_bf16((a[2] - mu) * rs * ga.z + ba.z,
                      (a[3] - mu) * rs * ga.w + ba.w);
    r.z = cvt_pk_bf16((a[4] - mu) * rs * gb.x + bb.x,
                      (a[5] - mu) * rs * gb.y + bb.y);
    r.w = cvt_pk_bf16((a[6] - mu) * rs * gb.z + bb.z,
                      (a[7] - mu) * rs * gb.w + bb.w);
    ((uint4*)(y1 + (size_t)n * DIM))[cg] = r;      // all 64 lanes store
}

// ---------------------------------------------------------------------------
// GEMM1 v9 = v8 structure (8-wave, 16 rows/wave, async-staged 32KB sB) with
// thinned epilogue: 7-op tanh GELU + 1-op HW bf16 converts.  grid = NPTS/128.
// ---------------------------------------------------------------------------
__global__ __launch_bounds__(512) void gemm1_kernel(
    const ushort* __restrict__ y1,    // N x 128 bf16
    const ushort* __restrict__ w1sw,  // 512 x 128 bf16 (n-major, pre-swizzled)
    const float*  __restrict__ b1,    // 512 fp32
    ushort*       __restrict__ y2,    // N x 512 bf16
    float*        __restrict__ ssq)   // 512 fp32
{
    __shared__ __align__(16) ushort sB[128 * 128];   // 32 KB
    __shared__ float sred[HID];
    const int tid = threadIdx.x;
    const int lane = tid & 63, wv = tid >> 6;        // wv 0..7
    const int lr = lane & 15, q = lane >> 4;
    const int m0 = blockIdx.x << 7;
    const int mw = m0 + (wv << 4);                   // 16 rows per wave

    if (tid < HID) sred[tid] = 0.f;

    // A fragments: lane holds row (mw + lr), k = ks*32 + q*8 .. +8
    bf16x8 af[4];
    {
        const ushort* a0 = y1 + (size_t)(mw + lr) * DIM + (q << 3);
        #pragma unroll
        for (int ks = 0; ks < 4; ++ks)
            af[ks] = *(const bf16x8*)(a0 + ks * 32);
    }

    #pragma unroll 1
    for (int nt = 0; nt < 4; ++nt) {
        // async stage B n-tile: wave wv covers LDS [wv*4KB, +4KB) in 4x1KB
        {
            const char* gsrc = (const char*)w1sw + (nt << 15) + (wv << 12) + (lane << 4);
            char* lb = (char*)sB + (wv << 12);
            #pragma unroll
            for (int j = 0; j < 4; ++j)
                cp16(gsrc + (j << 10), lb + (j << 10));
        }
        float b1v[8];
        #pragma unroll
        for (int ct = 0; ct < 8; ++ct) b1v[ct] = b1[(nt << 7) + (ct << 4) + lr];
        __syncthreads();

        f32x4 acc[8];
        #pragma unroll
        for (int ct = 0; ct < 8; ++ct) { f32x4 z = {0.f,0.f,0.f,0.f}; acc[ct] = z; }

        #pragma unroll
        for (int ct = 0; ct < 8; ++ct)
            #pragma unroll
            for (int ks = 0; ks < 4; ++ks) {
                const int cidx = ((((ks << 2) + q) ^ lr) << 3);
                bf16x8 bfv = *(const bf16x8*)(sB + ((ct << 4) + lr) * 128 + cidx);
                acc[ct] = __builtin_amdgcn_mfma_f32_16x16x32_bf16(af[ks], bfv, acc[ct], 0, 0, 0);
            }

        // epilogue for this n-tile: bias + tanh GELU + store + ssq partials
        #pragma unroll
        for (int ct = 0; ct < 8; ++ct) {
            const int col = (nt << 7) + (ct << 4) + lr;
            float ss = 0.f;
            #pragma unroll
            for (int r = 0; r < 4; ++r) {
                float g = gelu_f(acc[ct][r] + b1v[ct]);
                y2[(size_t)(mw + (q << 2) + r) * HID + col] = (ushort)cvt_pk_bf16(g, g);
                ss += g * g;
            }
            ss += __shfl_xor(ss, 16);
            ss += __shfl_xor(ss, 32);
            if (q == 0) atomicAdd(&sred[col], ss);
        }
        __syncthreads();
    }

    if (tid < HID) atomicAdd(&ssq[tid], sred[tid]);
}

// ---------------------------------------------------------------------------
// GRN scale: s[c] = grn_g[c] * nx[c] + 1
// ---------------------------------------------------------------------------
__global__ void grn_prep_kernel(const float* __restrict__ ssq,
                                const float* __restrict__ grn_g,
                                float* __restrict__ s)
{
    __shared__ float red[9];
    const int tid = threadIdx.x;
    const float gx = sqrtf(ssq[tid]);
    float v = gx;
    #pragma unroll
    for (int m = 1; m < 64; m <<= 1) v += __shfl_xor(v, m);
    if ((tid & 63) == 0) red[tid >> 6] = v;
    __syncthreads();
    if (tid == 0) {
        float t = 0.f;
        for (int i = 0; i < 8; ++i) t += red[i];
        red[8] = t;
    }
    __syncthreads();
    const float mean = red[8] * (1.f / 512.f);
    s[tid] = grn_g[tid] * (gx / (mean + 1e-6f)) + 1.0f;
}

// ---------------------------------------------------------------------------
// Fold GRN scale into w2 -> w2sw (n-major, bf16, PRE-SWIZZLED for linear
// global_load_lds staging) + constant bias vector.
// ---------------------------------------------------------------------------
__global__ __launch_bounds__(256) void prep_w2_kernel(
    const float* __restrict__ s,      // 512
    const float* __restrict__ w2,     // 512 x 128 fp32 (k-major)
    const float* __restrict__ grn_b,  // 512 fp32
    const float* __restrict__ b2,     // 128 fp32
    ushort*      __restrict__ w2sw,   // 128 x 512 bf16 (n-major, scaled, swz)
    float*       __restrict__ bvec)   // 128 fp32
{
    __shared__ float r4[4];
    const int j = blockIdx.x;
    const int tid = threadIdx.x;
    float part = 0.f;
    for (int k = tid; k < HID; k += 256) {
        float wv2 = w2[k * 128 + j];
        int kk = k >> 7, c = (k >> 3) & 15, jj = k & 7;
        w2sw[(kk << 14) + (j << 7) + ((c ^ (j & 15)) << 3) + jj] = f2bf(s[k] * wv2);
        part += grn_b[k] * wv2;
    }
    #pragma unroll
    for (int m = 1; m < 64; m <<= 1) part += __shfl_xor(part, m);
    if ((tid & 63) == 0) r4[tid >> 6] = part;
    __syncthreads();
    if (tid == 0)
        bvec[j] = r4[0] + r4[1] + r4[2] + r4[3] + b2[j];
}

// ---------------------------------------------------------------------------
// GEMM2 v9 = v8 structure (8-wave, 16 rows/wave); cvt_pk in epilogue.
// grid = NPTS/128.
// ---------------------------------------------------------------------------
__global__ __launch_bounds__(512) void gemm2_kernel(
    const ushort* __restrict__ y2,      // N x 512 bf16
    const ushort* __restrict__ w2sw,    // 128 x 512 bf16 (n-major, swz)
    const float*  __restrict__ bvec,    // 128
    const ushort* __restrict__ resid,   // N x 128 bf16
    float*        __restrict__ outf,    // N x 128 fp32 (or null)
    ushort*       __restrict__ xbfout)  // N x 128 bf16 (or null)
{
    __shared__ __align__(16) ushort sB[128 * 128];   // 32 KB: 128 n x 128 k chunk
    const int tid = threadIdx.x;
    const int lane = tid & 63, wv = tid >> 6;        // wv 0..7
    const int lr = lane & 15, q = lane >> 4;
    const int m0 = blockIdx.x << 7;
    const int mw = m0 + (wv << 4);                   // 16 rows per wave

    f32x4 acc[8];
    #pragma unroll
    for (int ct = 0; ct < 8; ++ct) { f32x4 z = {0.f,0.f,0.f,0.f}; acc[ct] = z; }

    const ushort* abase = y2 + (size_t)(mw + lr) * HID + (q << 3);

    #pragma unroll 1
    for (int kk = 0; kk < 4; ++kk) {
        // A frags for this K-chunk: issue first so HBM latency overlaps staging
        bf16x8 af[4];
        #pragma unroll
        for (int ks = 0; ks < 4; ++ks)
            af[ks] = *(const bf16x8*)(abase + (kk << 7) + ks * 32);

        // async stage B chunk: wave wv covers LDS [wv*4KB, +4KB) in 4x1KB
        {
            const char* gsrc = (const char*)w2sw + (kk << 15) + (wv << 12) + (lane << 4);
            char* lb = (char*)sB + (wv << 12);
            #pragma unroll
            for (int j = 0; j < 4; ++j)
                cp16(gsrc + (j << 10), lb + (j << 10));
        }
        __syncthreads();

        #pragma unroll
        for (int ct = 0; ct < 8; ++ct)
            #pragma unroll
            for (int ks = 0; ks < 4; ++ks) {
                const int cidx = ((((ks << 2) + q) ^ lr) << 3);
                bf16x8 bfv = *(const bf16x8*)(sB + ((ct << 4) + lr) * 128 + cidx);
                acc[ct] = __builtin_amdgcn_mfma_f32_16x16x32_bf16(af[ks], bfv, acc[ct], 0, 0, 0);
            }
        __syncthreads();
    }

    float bv[8];
    #pragma unroll
    for (int ct = 0; ct < 8; ++ct) bv[ct] = bvec[(ct << 4) + lr];

    #pragma unroll
    for (int r = 0; r < 4; ++r) {
        const int m = mw + (q << 2) + r;
        const size_t base = (size_t)m * DIM;
        #pragma unroll
        for (int ct = 0; ct < 8; ++ct) {
            const int j = (ct << 4) + lr;
            float v = acc[ct][r] + bv[ct] + bf2f(resid[base + j]);
            if (outf)   outf[base + j] = v;
            if (xbfout) xbfout[base + j] = (ushort)cvt_pk_bf16(v, v);
        }
    }
}

// ---------------------------------------------------------------------------
extern "C" void kernel_launch(void* const* d_in, const int* in_sizes, int n_in,
                              void* d_out, int out_size, void* d_ws, size_t ws_size,
                              hipStream_t stream)
{
    const float* feats = (const float*)d_in[0];
    const float* w_dw  = (const float*)d_in[1];
    const float* b_dw  = (const float*)d_in[2];
    const float* ln_g  = (const float*)d_in[3];
    const float* ln_b  = (const float*)d_in[4];
    const float* w1    = (const float*)d_in[5];
    const float* b1    = (const float*)d_in[6];
    const float* grn_g = (const float*)d_in[7];
    const float* grn_b = (const float*)d_in[8];
    const float* w2    = (const float*)d_in[9];
    const float* b2    = (const float*)d_in[10];
    const int*   nbr   = (const int*)d_in[11];

    char* ws = (char*)d_ws;
    size_t o = 0;
    ushort* y2    = (ushort*)(ws + o); o += (size_t)NPTS * HID * 2;        // 160 MB
    ushort* y1    = (ushort*)(ws + o); o += (size_t)NPTS * DIM * 2;        //  40 MB
    ushort* xbf   = (ushort*)(ws + o); o += (size_t)NPTS * DIM * 2;        //  40 MB
    int*    wl    = (int*)   (ws + o); o += ((size_t)NPTS * 64 + 64) * 4;  //  41 MB
    int*    cnts  = (int*)   (ws + o); o += (size_t)NPTS * 4;
    ushort* w1sw  = (ushort*)(ws + o); o += (size_t)HID * DIM * 2;
    ushort* w2sw  = (ushort*)(ws + o); o += (size_t)HID * DIM * 2;
    float*  sbuf  = (float*) (ws + o); o += 2048;
    float*  ssq   = (float*) (ws + o); o += 2048;
    float*  bvec  = (float*) (ws + o); o += 512;

    cast_bf16_kernel<<<NPTS * DIM / 4 / 256, 256, 0, stream>>>(feats, xbf);
    compact2_kernel<<<NPTS / 4, 256, 0, stream>>>(nbr, wl, cnts);

    for (int l = 0; l < DEPTH; ++l) {
        const float* wdw_l = w_dw  + (size_t)l * KK2 * DIM;
        const float* bdw_l = b_dw  + (size_t)l * DIM;
        const float* lng_l = ln_g  + (size_t)l * DIM;
        const float* lnb_l = ln_b  + (size_t)l * DIM;
        const float* w1_l  = w1    + (size_t)l * DIM * HID;
        const float* b1_l  = b1    + (size_t)l * HID;
        const float* gg_l  = grn_g + (size_t)l * HID;
        const float* gb_l  = grn_b + (size_t)l * HID;
        const float* w2_l  = w2    + (size_t)l * HID * DIM;
        const float* b2_l  = b2    + (size_t)l * DIM;

        w1t_kernel<<<512, 128, 0, stream>>>(w1_l, w1sw, ssq);
        dwln5_kernel<<<NPTS / 64, 1024, 0, stream>>>(
            xbf, wl, cnts, wdw_l, bdw_l, lng_l, lnb_l, y1);
        gemm1_kernel<<<NPTS / 128, 512, 0, stream>>>(y1, w1sw, b1_l, y2, ssq);
        grn_prep_kernel<<<1, 512, 0, stream>>>(ssq, gg_l, sbuf);
        prep_w2_kernel<<<128, 256, 0, stream>>>(sbuf, w2_l, gb_l, b2_l, w2sw, bvec);
        if (l == 0) {
            gemm2_kernel<<<NPTS / 128, 512, 0, stream>>>(
                y2, w2sw, bvec, xbf, nullptr, xbf);
        } else {
            gemm2_kernel<<<NPTS / 128, 512, 0, stream>>>(
                y2, w2sw, bvec, xbf, (float*)d_out, nullptr);
        }
    }
}

// Round 12
// 612.074 us; speedup vs baseline: 2.4352x; 1.0031x over previous
//
#include <hip/hip_runtime.h>
#include <hip/hip_bf16.h>

// Problem constants (from reference)
#define NPTS   160000    // B*P = 4*40000
#define DIM    128
#define HID    512
#define KK2    49        // 7x7
#define DEPTH  2

typedef __attribute__((ext_vector_type(8))) short bf16x8;
typedef __attribute__((ext_vector_type(4))) float f32x4;

static __device__ __forceinline__ ushort f2bf(float f) {
    unsigned u = __float_as_uint(f);
    return (ushort)((u + 0x7fffu + ((u >> 16) & 1u)) >> 16);
}
static __device__ __forceinline__ float bf2f(ushort h) {
    return __uint_as_float(((unsigned)h) << 16);
}
static __device__ __forceinline__ float lo16(unsigned u) { return __uint_as_float(u << 16); }
static __device__ __forceinline__ float hi16(unsigned u) { return __uint_as_float(u & 0xffff0000u); }

// HW packed f32->bf16 convert (RTNE, same rounding as f2bf): 1 VALU op
// replaces the 5-op manual rounding (and ~10-op pair packs).
static __device__ __forceinline__ unsigned cvt_pk_bf16(float lo, float hi) {
    unsigned r;
    asm("v_cvt_pk_bf16_f32 %0, %1, %2" : "=v"(r) : "v"(lo), "v"(hi));
    return r;
}

// async global->LDS copy, 16B per lane; LDS dest = wave-uniform base + lane*16
static __device__ __forceinline__ void cp16(const void* g, void* l) {
    __builtin_amdgcn_global_load_lds(
        (const __attribute__((address_space(1))) unsigned int*)g,
        (__attribute__((address_space(3))) unsigned int*)l,
        16, 0, 0);
}

// GELU, tanh form folded to 7 VALU ops (one v_exp, no fabs/copysign):
//   gelu(v) = v - v / (exp2(v*(a + b v^2)) + 1),  a=2*log2e*0.79788456,
//   b = a*0.044715.  Max |diff| vs exact-erf GELU ~3e-4 -- an order below
//   bf16 ulp at the magnitudes involved.  Branch-free, saturates correctly.
static __device__ __forceinline__ float gelu_f(float v) {
    float x2 = v * v;
    float u  = v * fmaf(x2, 0.1029435f, 2.3022082f);
    float t  = __builtin_amdgcn_exp2f(u);
    float r  = __builtin_amdgcn_rcpf(t + 1.0f);
    return fmaf(-v, r, v);
}

// ---------------------------------------------------------------------------
// fp32 -> bf16 cast (4 elems/thread), exact-size grid
// ---------------------------------------------------------------------------
__global__ __launch_bounds__(256) void cast_bf16_kernel(
    const float* __restrict__ x, ushort* __restrict__ o)
{
    int i = blockIdx.x * 256 + threadIdx.x;
    float4 v = ((const float4*)x)[i];
    uint2 r;
    r.x = cvt_pk_bf16(v.x, v.y);
    r.y = cvt_pk_bf16(v.z, v.w);
    ((uint2*)o)[i] = r;
}

// ---------------------------------------------------------------------------
// w1 (128x512 fp32) -> w1sw: 512x128 bf16 n-major, PRE-SWIZZLED so that a
// linear global_load_lds copy reproduces the XOR-swizzled LDS image the GEMM
// read path expects.  Also zeros ssq.
// ---------------------------------------------------------------------------
__global__ void w1t_kernel(const float* __restrict__ w1, ushort* __restrict__ w1sw,
                           float* __restrict__ ssq) {
    int n = blockIdx.x;            // 0..511 (output col)
    int k = threadIdx.x;           // 0..127 (reduction dim)
    int c = k >> 3, jj = k & 7;
    int dst = ((n >> 7) << 14) + ((n & 127) << 7) + ((c ^ (n & 15)) << 3) + jj;
    w1sw[dst] = f2bf(w1[k * 512 + n]);
    if (n < 4) ssq[n * 128 + k] = 0.f;
}

// ---------------------------------------------------------------------------
// Compact valid neighbor taps:
//   entry = idx*256 + tap   (idx*256 = byte offset of X row; tap in low 8b)
// wl stride = 64 ints/token; row[lane] for lane >= cnt = 49 (idx 0, tap 49 =
// zero weight row -> unconditional gathers are safe).  cnts[n] = cnt.
// ---------------------------------------------------------------------------
__global__ __launch_bounds__(256) void compact2_kernel(
    const int* __restrict__ nbr, int* __restrict__ wl, int* __restrict__ cnts)
{
    const int tid = threadIdx.x, lane = tid & 63, wv = tid >> 6;
    const int n = blockIdx.x * 4 + wv;
    int idx = (lane < KK2) ? nbr[(size_t)n * KK2 + lane] : NPTS;
    bool valid = idx < NPTS;
    unsigned long long mask = __ballot(valid);
    int cnt = __popcll(mask);
    int pos = __popcll(mask & ((1ull << lane) - 1ull));
    int* row = wl + (size_t)n * 64;
    if (lane >= cnt) row[lane] = 49;              // disjoint from valid writes
    if (valid) row[pos] = (idx << 8) | lane;
    if (lane == 0) cnts[n] = cnt;
}

// ---------------------------------------------------------------------------
// Depthwise sparse conv + LayerNorm, v5 + cvt_pk pack epilogue.
// ---------------------------------------------------------------------------
__global__ __launch_bounds__(1024, 8) void dwln5_kernel(
    const ushort* __restrict__ X,      // N x 128 bf16
    const int*    __restrict__ wl,     // N x 64 entries (padded with 49)
    const int*    __restrict__ cnts,   // N
    const float*  __restrict__ wdw,    // 49 x 128 fp32
    const float*  __restrict__ bdw,    // 128
    const float*  __restrict__ lng,    // 128
    const float*  __restrict__ lnb,    // 128
    ushort*       __restrict__ y1)     // N x 128 bf16
{
    __shared__ __align__(16) float wsm[16 * 404];   // [cg] stride 404, [tap][8]
    __shared__ int wle[64 * 68];                    // entry lists, stride 68
    const int tid = threadIdx.x;
    #pragma unroll
    for (int i0 = 0; i0 < 2048; i0 += 1024) {
        int i = i0 + tid;
        if (i < 1568) {
            int tap = i >> 5, rem = i & 31, cg = rem >> 1, q = rem & 1;
            ((float4*)wsm)[cg * 101 + tap * 2 + q] = ((const float4*)wdw)[i];
        }
    }
    if (tid < 32) {
        float4 z = {0.f, 0.f, 0.f, 0.f};
        int cg = tid >> 1, q = tid & 1;
        ((float4*)wsm)[cg * 101 + 98 + q] = z;     // tap 49 = zeros
    }
    {
        const int* src = wl + (size_t)blockIdx.x * 4096;
        #pragma unroll
        for (int m = 0; m < 4; ++m) {
            int idx = tid + (m << 10);
            wle[(idx >> 6) * 68 + (idx & 63)] = src[idx];
        }
    }
    __syncthreads();

    const int lane = tid & 63, wv = tid >> 6;
    const int g = lane >> 4, cg = lane & 15;
    const int li = (wv << 2) + g;                 // local token 0..63
    const int n = blockIdx.x * 64 + li;

    int myc = cnts[n];
    int rmax = max(myc, __shfl_xor(myc, 16));
    rmax = max(rmax, __shfl_xor(rmax, 32));

    const int* ep = wle + li * 68;
    const float* wcg = wsm + cg * 404;
    const char* Xb = (const char*)X + (cg << 4);

    float a[8] = {0.f, 0.f, 0.f, 0.f, 0.f, 0.f, 0.f, 0.f};

    int e0 = ep[0], e1 = ep[1], e2 = ep[2];
    uint4 x0 = *(const uint4*)(Xb + (e0 & ~255));
    uint4 x1 = *(const uint4*)(Xb + (e1 & ~255));
    uint4 x2 = *(const uint4*)(Xb + (e2 & ~255));

    for (int r = 0; r < rmax; ++r) {
        int e3 = ep[r + 3];                       // r+3 <= 51 < 64, broadcast
        uint4 x3 = *(const uint4*)(Xb + (e3 & ~255));
        const float* wp = wcg + (e0 & 255) * 8;
        float4 wa = *(const float4*)wp;
        float4 wb = *(const float4*)(wp + 4);
        a[0] += lo16(x0.x) * wa.x;  a[1] += hi16(x0.x) * wa.y;
        a[2] += lo16(x0.y) * wa.z;  a[3] += hi16(x0.y) * wa.w;
        a[4] += lo16(x0.z) * wb.x;  a[5] += hi16(x0.z) * wb.y;
        a[6] += lo16(x0.w) * wb.z;  a[7] += hi16(x0.w) * wb.w;
        e0 = e1; e1 = e2; e2 = e3;
        x0 = x1; x1 = x2; x2 = x3;
    }

    const float4 bda = ((const float4*)bdw)[cg * 2];
    const float4 bdb = ((const float4*)bdw)[cg * 2 + 1];
    a[0] += bda.x; a[1] += bda.y; a[2] += bda.z; a[3] += bda.w;
    a[4] += bdb.x; a[5] += bdb.y; a[6] += bdb.z; a[7] += bdb.w;

    float s1 = 0.f, s2 = 0.f;
    #pragma unroll
    for (int j = 0; j < 8; ++j) { s1 += a[j]; s2 += a[j] * a[j]; }
    #pragma unroll
    for (int m = 1; m < 16; m <<= 1) {
        s1 += __shfl_xor(s1, m);
        s2 += __shfl_xor(s2, m);
    }
    const float mu  = s1 * (1.f / 128.f);
    const float var = s2 * (1.f / 128.f) - mu * mu;
    const float rs  = rsqrtf(var + 1e-6f);

    const float4 ga = ((const float4*)lng)[cg * 2];
    const float4 gb = ((const float4*)lng)[cg * 2 + 1];
    const float4 ba = ((const float4*)lnb)[cg * 2];
    const float4 bb = ((const float4*)lnb)[cg * 2 + 1];
    uint4 r;
    r.x = cvt_pk_bf16((a[0] - mu) * rs * ga.x + ba.x,
                      (a[1] - mu) * rs * ga.y + ba.y);
    r.y = cvt_pk_bf16((a[2] - mu) * rs * ga.z + ba.z,
                      (a[3] - mu) * rs * ga.w + ba.w);
    r.z = cvt_pk_bf16((a[4] - mu) * rs * gb.x + bb.x,
                      (a[5] - mu) * rs * gb.y + bb.y);
    r.w = cvt_pk_bf16((a[6] - mu) * rs * gb.z + bb.z,
                      (a[7] - mu) * rs * gb.w + bb.w);
    ((uint4*)(y1 + (size_t)n * DIM))[cg] = r;      // all 64 lanes store
}

// ---------------------------------------------------------------------------
// GEMM1 v9 = v8 structure (8-wave, 16 rows/wave, async-staged 32KB sB) with
// thinned epilogue: 7-op tanh GELU + 1-op HW bf16 converts.  grid = NPTS/128.
// ---------------------------------------------------------------------------
__global__ __launch_bounds__(512) void gemm1_kernel(
    const ushort* __restrict__ y1,    // N x 128 bf16
    const ushort* __restrict__ w1sw,  // 512 x 128 bf16 (n-major, pre-swizzled)
    const float*  __restrict__ b1,    // 512 fp32
    ushort*       __restrict__ y2,    // N x 512 bf16
    float*        __restrict__ ssq)   // 512 fp32
{
    __shared__ __align__(16) ushort sB[128 * 128];   // 32 KB
    __shared__ float sred[HID];
    const int tid = threadIdx.x;
    const int lane = tid & 63, wv = tid >> 6;        // wv 0..7
    const int lr = lane & 15, q = lane >> 4;
    const int m0 = blockIdx.x << 7;
    const int mw = m0 + (wv << 4);                   // 16 rows per wave

    if (tid < HID) sred[tid] = 0.f;

    // A fragments: lane holds row (mw + lr), k = ks*32 + q*8 .. +8
    bf16x8 af[4];
    {
        const ushort* a0 = y1 + (size_t)(mw + lr) * DIM + (q << 3);
        #pragma unroll
        for (int ks = 0; ks < 4; ++ks)
            af[ks] = *(const bf16x8*)(a0 + ks * 32);
    }

    #pragma unroll 1
    for (int nt = 0; nt < 4; ++nt) {
        // async stage B n-tile: wave wv covers LDS [wv*4KB, +4KB) in 4x1KB
        {
            const char* gsrc = (const char*)w1sw + (nt << 15) + (wv << 12) + (lane << 4);
            char* lb = (char*)sB + (wv << 12);
            #pragma unroll
            for (int j = 0; j < 4; ++j)
                cp16(gsrc + (j << 10), lb + (j << 10));
        }
        float b1v[8];
        #pragma unroll
        for (int ct = 0; ct < 8; ++ct) b1v[ct] = b1[(nt << 7) + (ct << 4) + lr];
        __syncthreads();

        f32x4 acc[8];
        #pragma unroll
        for (int ct = 0; ct < 8; ++ct) { f32x4 z = {0.f,0.f,0.f,0.f}; acc[ct] = z; }

        #pragma unroll
        for (int ct = 0; ct < 8; ++ct)
            #pragma unroll
            for (int ks = 0; ks < 4; ++ks) {
                const int cidx = ((((ks << 2) + q) ^ lr) << 3);
                bf16x8 bfv = *(const bf16x8*)(sB + ((ct << 4) + lr) * 128 + cidx);
                acc[ct] = __builtin_amdgcn_mfma_f32_16x16x32_bf16(af[ks], bfv, acc[ct], 0, 0, 0);
            }

        // epilogue for this n-tile: bias + tanh GELU + store + ssq partials
        #pragma unroll
        for (int ct = 0; ct < 8; ++ct) {
            const int col = (nt << 7) + (ct << 4) + lr;
            float ss = 0.f;
            #pragma unroll
            for (int r = 0; r < 4; ++r) {
                float g = gelu_f(acc[ct][r] + b1v[ct]);
                y2[(size_t)(mw + (q << 2) + r) * HID + col] = (ushort)cvt_pk_bf16(g, g);
                ss += g * g;
            }
            ss += __shfl_xor(ss, 16);
            ss += __shfl_xor(ss, 32);
            if (q == 0) atomicAdd(&sred[col], ss);
        }
        __syncthreads();
    }

    if (tid < HID) atomicAdd(&ssq[tid], sred[tid]);
}

// ---------------------------------------------------------------------------
// GRN scale: s[c] = grn_g[c] * nx[c] + 1
// ---------------------------------------------------------------------------
__global__ void grn_prep_kernel(const float* __restrict__ ssq,
                                const float* __restrict__ grn_g,
                                float* __restrict__ s)
{
    __shared__ float red[9];
    const int tid = threadIdx.x;
    const float gx = sqrtf(ssq[tid]);
    float v = gx;
    #pragma unroll
    for (int m = 1; m < 64; m <<= 1) v += __shfl_xor(v, m);
    if ((tid & 63) == 0) red[tid >> 6] = v;
    __syncthreads();
    if (tid == 0) {
        float t = 0.f;
        for (int i = 0; i < 8; ++i) t += red[i];
        red[8] = t;
    }
    __syncthreads();
    const float mean = red[8] * (1.f / 512.f);
    s[tid] = grn_g[tid] * (gx / (mean + 1e-6f)) + 1.0f;
}

// ---------------------------------------------------------------------------
// Fold GRN scale into w2 -> w2sw (n-major, bf16, PRE-SWIZZLED for linear
// global_load_lds staging) + constant bias vector.
// ---------------------------------------------------------------------------
__global__ __launch_bounds__(256) void prep_w2_kernel(
    const float* __restrict__ s,      // 512
    const float* __restrict__ w2,     // 512 x 128 fp32 (k-major)
    const float* __restrict__ grn_b,  // 512 fp32
    const float* __restrict__ b2,     // 128 fp32
    ushort*      __restrict__ w2sw,   // 128 x 512 bf16 (n-major, scaled, swz)
    float*       __restrict__ bvec)   // 128 fp32
{
    __shared__ float r4[4];
    const int j = blockIdx.x;
    const int tid = threadIdx.x;
    float part = 0.f;
    for (int k = tid; k < HID; k += 256) {
        float wv2 = w2[k * 128 + j];
        int kk = k >> 7, c = (k >> 3) & 15, jj = k & 7;
        w2sw[(kk << 14) + (j << 7) + ((c ^ (j & 15)) << 3) + jj] = f2bf(s[k] * wv2);
        part += grn_b[k] * wv2;
    }
    #pragma unroll
    for (int m = 1; m < 64; m <<= 1) part += __shfl_xor(part, m);
    if ((tid & 63) == 0) r4[tid >> 6] = part;
    __syncthreads();
    if (tid == 0)
        bvec[j] = r4[0] + r4[1] + r4[2] + r4[3] + b2[j];
}

// ---------------------------------------------------------------------------
// GEMM2 v9 = v8 structure (8-wave, 16 rows/wave); cvt_pk in epilogue.
// grid = NPTS/128.
// ---------------------------------------------------------------------------
__global__ __launch_bounds__(512) void gemm2_kernel(
    const ushort* __restrict__ y2,      // N x 512 bf16
    const ushort* __restrict__ w2sw,    // 128 x 512 bf16 (n-major, swz)
    const float*  __restrict__ bvec,    // 128
    const ushort* __restrict__ resid,   // N x 128 bf16
    float*        __restrict__ outf,    // N x 128 fp32 (or null)
    ushort*       __restrict__ xbfout)  // N x 128 bf16 (or null)
{
    __shared__ __align__(16) ushort sB[128 * 128];   // 32 KB: 128 n x 128 k chunk
    const int tid = threadIdx.x;
    const int lane = tid & 63, wv = tid >> 6;        // wv 0..7
    const int lr = lane & 15, q = lane >> 4;
    const int m0 = blockIdx.x << 7;
    const int mw = m0 + (wv << 4);                   // 16 rows per wave

    f32x4 acc[8];
    #pragma unroll
    for (int ct = 0; ct < 8; ++ct) { f32x4 z = {0.f,0.f,0.f,0.f}; acc[ct] = z; }

    const ushort* abase = y2 + (size_t)(mw + lr) * HID + (q << 3);

    #pragma unroll 1
    for (int kk = 0; kk < 4; ++kk) {
        // A frags for this K-chunk: issue first so HBM latency overlaps staging
        bf16x8 af[4];
        #pragma unroll
        for (int ks = 0; ks < 4; ++ks)
            af[ks] = *(const bf16x8*)(abase + (kk << 7) + ks * 32);

        // async stage B chunk: wave wv covers LDS [wv*4KB, +4KB) in 4x1KB
        {
            const char* gsrc = (const char*)w2sw + (kk << 15) + (wv << 12) + (lane << 4);
            char* lb = (char*)sB + (wv << 12);
            #pragma unroll
            for (int j = 0; j < 4; ++j)
                cp16(gsrc + (j << 10), lb + (j << 10));
        }
        __syncthreads();

        #pragma unroll
        for (int ct = 0; ct < 8; ++ct)
            #pragma unroll
            for (int ks = 0; ks < 4; ++ks) {
                const int cidx = ((((ks << 2) + q) ^ lr) << 3);
                bf16x8 bfv = *(const bf16x8*)(sB + ((ct << 4) + lr) * 128 + cidx);
                acc[ct] = __builtin_amdgcn_mfma_f32_16x16x32_bf16(af[ks], bfv, acc[ct], 0, 0, 0);
            }
        __syncthreads();
    }

    float bv[8];
    #pragma unroll
    for (int ct = 0; ct < 8; ++ct) bv[ct] = bvec[(ct << 4) + lr];

    #pragma unroll
    for (int r = 0; r < 4; ++r) {
        const int m = mw + (q << 2) + r;
        const size_t base = (size_t)m * DIM;
        #pragma unroll
        for (int ct = 0; ct < 8; ++ct) {
            const int j = (ct << 4) + lr;
            float v = acc[ct][r] + bv[ct] + bf2f(resid[base + j]);
            if (outf)   outf[base + j] = v;
            if (xbfout) xbfout[base + j] = (ushort)cvt_pk_bf16(v, v);
        }
    }
}

// ---------------------------------------------------------------------------
extern "C" void kernel_launch(void* const* d_in, const int* in_sizes, int n_in,
                              void* d_out, int out_size, void* d_ws, size_t ws_size,
                              hipStream_t stream)
{
    const float* feats = (const float*)d_in[0];
    const float* w_dw  = (const float*)d_in[1];
    const float* b_dw  = (const float*)d_in[2];
    const float* ln_g  = (const float*)d_in[3];
    const float* ln_b  = (const float*)d_in[4];
    const float* w1    = (const float*)d_in[5];
    const float* b1    = (const float*)d_in[6];
    const float* grn_g = (const float*)d_in[7];
    const float* grn_b = (const float*)d_in[8];
    const float* w2    = (const float*)d_in[9];
    const float* b2    = (const float*)d_in[10];
    const int*   nbr   = (const int*)d_in[11];

    char* ws = (char*)d_ws;
    size_t o = 0;
    ushort* y2    = (ushort*)(ws + o); o += (size_t)NPTS * HID * 2;        // 160 MB
    ushort* y1    = (ushort*)(ws + o); o += (size_t)NPTS * DIM * 2;        //  40 MB
    ushort* xbf   = (ushort*)(ws + o); o += (size_t)NPTS * DIM * 2;        //  40 MB
    int*    wl    = (int*)   (ws + o); o += ((size_t)NPTS * 64 + 64) * 4;  //  41 MB
    int*    cnts  = (int*)   (ws + o); o += (size_t)NPTS * 4;
    ushort* w1sw  = (ushort*)(ws + o); o += (size_t)HID * DIM * 2;
    ushort* w2sw  = (ushort*)(ws + o); o += (size_t)HID * DIM * 2;
    float*  sbuf  = (float*) (ws + o); o += 2048;
    float*  ssq   = (float*) (ws + o); o += 2048;
    float*  bvec  = (float*) (ws + o); o += 512;

    cast_bf16_kernel<<<NPTS * DIM / 4 / 256, 256, 0, stream>>>(feats, xbf);
    compact2_kernel<<<NPTS / 4, 256, 0, stream>>>(nbr, wl, cnts);

    for (int l = 0; l < DEPTH; ++l) {
        const float* wdw_l = w_dw  + (size_t)l * KK2 * DIM;
        const float* bdw_l = b_dw  + (size_t)l * DIM;
        const float* lng_l = ln_g  + (size_t)l * DIM;
        const float* lnb_l = ln_b  + (size_t)l * DIM;
        const float* w1_l  = w1    + (size_t)l * DIM * HID;
        const float* b1_l  = b1    + (size_t)l * HID;
        const float* gg_l  = grn_g + (size_t)l * HID;
        const float* gb_l  = grn_b + (size_t)l * HID;
        const float* w2_l  = w2    + (size_t)l * HID * DIM;
        const float* b2_l  = b2    + (size_t)l * DIM;

        w1t_kernel<<<512, 128, 0, stream>>>(w1_l, w1sw, ssq);
        dwln5_kernel<<<NPTS / 64, 1024, 0, stream>>>(
            xbf, wl, cnts, wdw_l, bdw_l, lng_l, lnb_l, y1);
        gemm1_kernel<<<NPTS / 128, 512, 0, stream>>>(y1, w1sw, b1_l, y2, ssq);
        grn_prep_kernel<<<1, 512, 0, stream>>>(ssq, gg_l, sbuf);
        prep_w2_kernel<<<128, 256, 0, stream>>>(sbuf, w2_l, gb_l, b2_l, w2sw, bvec);
        if (l == 0) {
            gemm2_kernel<<<NPTS / 128, 512, 0, stream>>>(
                y2, w2sw, bvec, xbf, nullptr, xbf);
        } else {
            gemm2_kernel<<<NPTS / 128, 512, 0, stream>>>(
                y2, w2sw, bvec, xbf, (float*)d_out, nullptr);
        }
    }
}